// Round 4
// baseline (363.017 us; speedup 1.0000x reference)
//
#include <hip/hip_runtime.h>
#include <hip/hip_bf16.h>
#include <math.h>

#define LN_EPS 1e-5f
// dim^-0.5 * log2(e): folded into q so softmax is exp2(s) with no muls
#define QSCALE 0.09016844005556021f

typedef __attribute__((ext_vector_type(8))) short short8;
typedef __attribute__((ext_vector_type(4))) float f32x4;

__device__ inline ushort f2bf(float f) {
  __hip_bfloat16 h = __float2bfloat16(f);
  return *reinterpret_cast<ushort*>(&h);
}

// Shapes (fixed): b=8, n=2048/stream, 3 streams, dim=256, heads=8, d=32.
// xn (bf16): [8*6144][256].  q/k (bf16): [bh][2048][32].  vT (bf16): [bh][32][2048].
// osum (bf16): [b*2048][256].

// ---------------------- fused: LN-normalize -> bf16  +  weight cast -> bf16
__global__ __launch_bounds__(256) void ln_wcast_kernel(
    const float* __restrict__ x, const float* __restrict__ lng,
    const float* __restrict__ lnb,
    const float* __restrict__ Wq, const float* __restrict__ Wk,
    const float* __restrict__ Wv, const float* __restrict__ Wo,
    ushort* __restrict__ xn, ushort* __restrict__ wbf) {
  if (blockIdx.x < 256) {
    int t = blockIdx.x * 256 + threadIdx.x;
    int e0 = t * 4;
    int m = e0 >> 16, off = e0 & 65535;
    const float* src = (m == 0) ? Wq : (m == 1) ? Wk : (m == 2) ? Wv : Wo;
    float4 v = *(const float4*)(src + off);
    ushort4 o;
    o.x = f2bf(v.x); o.y = f2bf(v.y); o.z = f2bf(v.z); o.w = f2bf(v.w);
    *(ushort4*)(wbf + m * 65536 + off) = o;
    return;
  }
  int w = threadIdx.x >> 6;
  int lane = threadIdx.x & 63;
  size_t token = (size_t)(blockIdx.x - 256) * 4 + w;
  float4 v = *(const float4*)(x + token * 256 + lane * 4);
  float s  = v.x + v.y + v.z + v.w;
  float s2 = v.x * v.x + v.y * v.y + v.z * v.z + v.w * v.w;
#pragma unroll
  for (int off = 32; off >= 1; off >>= 1) {
    s  += __shfl_xor(s, off, 64);
    s2 += __shfl_xor(s2, off, 64);
  }
  float mu  = s * (1.0f / 256.0f);
  float var = s2 * (1.0f / 256.0f) - mu * mu;
  float rs  = rsqrtf(var + LN_EPS);
  float4 g = *(const float4*)(lng + lane * 4);
  float4 bb = *(const float4*)(lnb + lane * 4);
  ushort4 o;
  o.x = f2bf((v.x - mu) * rs * g.x + bb.x);
  o.y = f2bf((v.y - mu) * rs * g.y + bb.y);
  o.z = f2bf((v.z - mu) * rs * g.z + bb.z);
  o.w = f2bf((v.w - mu) * rs * g.w + bb.w);
  *(ushort4*)(xn + token * 256 + lane * 4) = o;
}

// ------------------------------------------------- QKV projections (MFMA)
// z: 0=q (scaled, C^T) 1=k_e (C^T) 2=v_e (C -> vT) 3=k_l 4=v_l
// No LDS; x-fragment loads double-buffered across token tiles.
__global__ __launch_bounds__(256) void proj_kernel(
    const ushort* __restrict__ xn,
    const ushort* __restrict__ wq, const ushort* __restrict__ wk,
    const ushort* __restrict__ wv,
    const float* __restrict__ bq, const float* __restrict__ bk,
    const float* __restrict__ bv,
    ushort* __restrict__ qb, ushort* __restrict__ keb, ushort* __restrict__ vTe,
    ushort* __restrict__ klb, ushort* __restrict__ vTl) {
  int z = blockIdx.z;
  const ushort* W; const float* bias; ushort* out; int s; bool isV; float scl;
  if (z == 0)      { W = wq; bias = bq; out = qb;  s = 0; isV = false; scl = QSCALE; }
  else if (z == 1) { W = wk; bias = bk; out = keb; s = 1; isV = false; scl = 1.0f; }
  else if (z == 2) { W = wv; bias = bv; out = vTe; s = 1; isV = true;  scl = 1.0f; }
  else if (z == 3) { W = wk; bias = bk; out = klb; s = 2; isV = false; scl = 1.0f; }
  else             { W = wv; bias = bv; out = vTl; s = 2; isV = true;  scl = 1.0f; }

  int tid = threadIdx.x;
  int w = tid >> 6, lane = tid & 63;
  int n = lane & 15, quad = lane >> 4;
  int cbase = blockIdx.y * 128 + w * 32;

  short8 wfrag[2][8];
#pragma unroll
  for (int ct = 0; ct < 2; ++ct)
#pragma unroll
    for (int kc = 0; kc < 8; ++kc)
      wfrag[ct][kc] = *(const short8*)(W + (size_t)(cbase + ct * 16 + n) * 256 + kc * 32 + quad * 8);
  float4 bt[2]; float bsc[2];
  if (!isV) {
    bt[0] = *(const float4*)(bias + cbase + quad * 4);
    bt[1] = *(const float4*)(bias + cbase + 16 + quad * 4);
  } else {
    bsc[0] = bias[cbase + n];
    bsc[1] = bias[cbase + 16 + n];
  }

  short8 xfA[8], xfB[8];
  {
    int tok = blockIdx.x * 128 + n;
    int b = tok >> 11, n2 = tok & 2047;
    const ushort* xrow = xn + ((size_t)b * 6144 + s * 2048 + n2) * 256;
#pragma unroll
    for (int kc = 0; kc < 8; ++kc)
      xfA[kc] = *(const short8*)(xrow + kc * 32 + quad * 8);
  }

#pragma unroll
  for (int tt = 0; tt < 8; ++tt) {
    short8* cur = (tt & 1) ? xfB : xfA;
    short8* nxt = (tt & 1) ? xfA : xfB;
    if (tt < 7) {
      int tok = blockIdx.x * 128 + (tt + 1) * 16 + n;
      int b = tok >> 11, n2 = tok & 2047;
      const ushort* xrow = xn + ((size_t)b * 6144 + s * 2048 + n2) * 256;
#pragma unroll
      for (int kc = 0; kc < 8; ++kc)
        nxt[kc] = *(const short8*)(xrow + kc * 32 + quad * 8);
    }
    int t0 = blockIdx.x * 128 + tt * 16;
    int tok = t0 + n;
    int b = tok >> 11, n2 = tok & 2047;
    f32x4 acc[2] = {{0.f, 0.f, 0.f, 0.f}, {0.f, 0.f, 0.f, 0.f}};
#pragma unroll
    for (int ct = 0; ct < 2; ++ct)
#pragma unroll
      for (int kc = 0; kc < 8; ++kc)
        acc[ct] = isV
          ? __builtin_amdgcn_mfma_f32_16x16x32_bf16(cur[kc], wfrag[ct][kc], acc[ct], 0, 0, 0)
          : __builtin_amdgcn_mfma_f32_16x16x32_bf16(wfrag[ct][kc], cur[kc], acc[ct], 0, 0, 0);

    if (!isV) {
#pragma unroll
      for (int ct = 0; ct < 2; ++ct) {
        int c = cbase + ct * 16 + quad * 4;
        int h = c >> 5, d = c & 31;
        float* bp = (float*)&bt[ct];
        ushort4 st;
        st.x = f2bf((acc[ct][0] + bp[0]) * scl);
        st.y = f2bf((acc[ct][1] + bp[1]) * scl);
        st.z = f2bf((acc[ct][2] + bp[2]) * scl);
        st.w = f2bf((acc[ct][3] + bp[3]) * scl);
        *(ushort4*)(out + (((size_t)(b * 8 + h) * 2048) + n2) * 32 + d) = st;
      }
    } else {
      int tq0 = t0 + quad * 4;
      int b2 = tq0 >> 11, n2q = tq0 & 2047;
#pragma unroll
      for (int ct = 0; ct < 2; ++ct) {
        int c = cbase + ct * 16 + n;
        int h = c >> 5, d = c & 31;
        ushort4 st;
        st.x = f2bf(acc[ct][0] + bsc[ct]);
        st.y = f2bf(acc[ct][1] + bsc[ct]);
        st.z = f2bf(acc[ct][2] + bsc[ct]);
        st.w = f2bf(acc[ct][3] + bsc[ct]);
        *(ushort4*)(out + (((size_t)(b2 * 8 + h) * 32) + d) * 2048 + n2q) = st;
      }
    }
  }
}

// ------------------------------------------------ flash attention bf16 MFMA
// NO LDS staging, NO barriers: K and V^T fragments are loaded directly from
// global in MFMA A-operand layout (L1 serves the 4x intra-block reuse).
// 128 q-rows per block (2 q-groups per wave) amortize K/V reads 2x.
// Per-wave LDS only for the P^T round-trip and the output transpose.
// XCD-swizzled block ids: each bh's 16 q-blocks land on one XCD (L2 reuse).
__global__ __launch_bounds__(256) void attn_kernel(
    const ushort* __restrict__ q,
    const ushort* __restrict__ ke, const ushort* __restrict__ vTe,
    const ushort* __restrict__ kl, const ushort* __restrict__ vTl,
    ushort* __restrict__ osum) {
  __shared__ __align__(16) short Pt[4][2][16 * 72];  // [wave][qgroup][qrow][64+8pad]

  int tid = threadIdx.x;
  int w = tid >> 6, lane = tid & 63;
  int n = lane & 15, quad = lane >> 4;

  // swizzle: linear id -> (bh, q-block) so one bh stays on one XCD (id%8)
  int lin = blockIdx.y * 16 + blockIdx.x;
  int g = (lin & 7) * 128 + (lin >> 3);
  int bh = g >> 4;
  int q0 = (g & 15) * 128;

  short8 qfrag[2];
  qfrag[0] = *(const short8*)(q + ((size_t)bh * 2048 + q0 + w * 16 + n) * 32 + quad * 8);
  qfrag[1] = *(const short8*)(q + ((size_t)bh * 2048 + q0 + 64 + w * 16 + n) * 32 + quad * 8);

  f32x4 out_acc[2][2] = {{{0.f,0.f,0.f,0.f},{0.f,0.f,0.f,0.f}},
                         {{0.f,0.f,0.f,0.f},{0.f,0.f,0.f,0.f}}};

  for (int s = 0; s < 2; ++s) {
    const ushort* K  = (s == 0 ? ke : kl) + (size_t)bh * 2048 * 32;
    const ushort* VT = (s == 0 ? vTe : vTl) + (size_t)bh * 32 * 2048;
    float l[2] = {0.f, 0.f};
    f32x4 oacc[2][2] = {{{0.f,0.f,0.f,0.f},{0.f,0.f,0.f,0.f}},
                        {{0.f,0.f,0.f,0.f},{0.f,0.f,0.f,0.f}}};

    for (int jt = 0; jt < 32; ++jt) {
      int kt0 = jt * 64;
      // K fragments: A[m=key(t4*16+n)][k=d(quad*8+j)] -- contiguous 16B rows
      short8 kf[4];
#pragma unroll
      for (int t4 = 0; t4 < 4; ++t4)
        kf[t4] = *(const short8*)(K + (size_t)(kt0 + t4 * 16 + n) * 32 + quad * 8);
      // V^T fragments: A[m=d(dh*16+n)][k=key(kc*32+quad*8+j)]
      short8 vf[2][2];
#pragma unroll
      for (int dh = 0; dh < 2; ++dh)
#pragma unroll
        for (int kc = 0; kc < 2; ++kc)
          vf[dh][kc] = *(const short8*)(VT + (size_t)(dh * 16 + n) * 2048 + kt0 + kc * 32 + quad * 8);

      // S^T = K q^T for both q-groups (kf shared)
      f32x4 sacc[2][4];
#pragma unroll
      for (int gq = 0; gq < 2; ++gq)
#pragma unroll
        for (int t4 = 0; t4 < 4; ++t4) {
          f32x4 z = {0.f, 0.f, 0.f, 0.f};
          sacc[gq][t4] = __builtin_amdgcn_mfma_f32_16x16x32_bf16(kf[t4], qfrag[gq], z, 0, 0, 0);
        }

      // softmax weights p = exp2(s); per-lane rows, 2-shuffle sum
#pragma unroll
      for (int gq = 0; gq < 2; ++gq) {
        float ls = 0.f;
#pragma unroll
        for (int t4 = 0; t4 < 4; ++t4) {
          float p0 = __builtin_amdgcn_exp2f(sacc[gq][t4][0]);
          float p1 = __builtin_amdgcn_exp2f(sacc[gq][t4][1]);
          float p2 = __builtin_amdgcn_exp2f(sacc[gq][t4][2]);
          float p3 = __builtin_amdgcn_exp2f(sacc[gq][t4][3]);
          ls += p0 + p1 + p2 + p3;
          ushort4 pk;
          pk.x = f2bf(p0); pk.y = f2bf(p1); pk.z = f2bf(p2); pk.w = f2bf(p3);
          *(ushort4*)&Pt[w][gq][n * 72 + t4 * 16 + quad * 4] = pk;
        }
        ls += __shfl_xor(ls, 16, 64);
        ls += __shfl_xor(ls, 32, 64);
        l[gq] += ls;
      }

      // O^T += V^T P^T  (vf shared across q-groups)
#pragma unroll
      for (int gq = 0; gq < 2; ++gq)
#pragma unroll
        for (int kc = 0; kc < 2; ++kc) {
          short8 bfrag = *(const short8*)&Pt[w][gq][n * 72 + kc * 32 + quad * 8];
#pragma unroll
          for (int dh = 0; dh < 2; ++dh)
            oacc[gq][dh] = __builtin_amdgcn_mfma_f32_16x16x32_bf16(vf[dh][kc], bfrag, oacc[gq][dh], 0, 0, 0);
        }
    }
#pragma unroll
    for (int gq = 0; gq < 2; ++gq) {
      float inv = 1.0f / l[gq];
      out_acc[gq][0] += oacc[gq][0] * inv;
      out_acc[gq][1] += oacc[gq][1] * inv;
    }
  }

  // transpose O^T -> O per wave/group via Pt region (16x36 fp32 fits exactly)
  int b = bh >> 3, h = bh & 7;
  int qrow = lane >> 2, c4 = (lane & 3) * 4;
#pragma unroll
  for (int gq = 0; gq < 2; ++gq) {
    float* Os = (float*)&Pt[w][gq][0];
#pragma unroll
    for (int dh = 0; dh < 2; ++dh)
      *(f32x4*)&Os[n * 36 + dh * 16 + quad * 4] = out_acc[gq][dh];
    ushort* orow = osum + ((size_t)b * 2048 + q0 + gq * 64 + w * 16 + qrow) * 256 + h * 32;
#pragma unroll
    for (int off = 0; off < 32; off += 16) {
      f32x4 vv = *(f32x4*)&Os[qrow * 36 + off + c4];
      ushort4 st;
      st.x = f2bf(vv[0]); st.y = f2bf(vv[1]); st.z = f2bf(vv[2]); st.w = f2bf(vv[3]);
      *(ushort4*)(orow + off + c4) = st;
    }
  }
}

// ------------------------------------------- output projection (MFMA, C^T)
// out[t][c] = sum_k osum[t][k]*Wo[c][k] + 2*bo[c], fp32 out.
// 64 tokens/block (512 blocks), x-fragment double-buffered.
__global__ __launch_bounds__(256) void outproj_kernel(
    const ushort* __restrict__ osum, const ushort* __restrict__ wo,
    const float* __restrict__ bo, float* __restrict__ out) {
  int tid = threadIdx.x;
  int w = tid >> 6, lane = tid & 63;
  int n = lane & 15, quad = lane >> 4;
  int cbase = blockIdx.y * 128 + w * 32;

  short8 wfrag[2][8];
#pragma unroll
  for (int ct = 0; ct < 2; ++ct)
#pragma unroll
    for (int kc = 0; kc < 8; ++kc)
      wfrag[ct][kc] = *(const short8*)(wo + (size_t)(cbase + ct * 16 + n) * 256 + kc * 32 + quad * 8);
  float4 bt[2];
  bt[0] = *(const float4*)(bo + cbase + quad * 4);
  bt[1] = *(const float4*)(bo + cbase + 16 + quad * 4);

  short8 xfA[8], xfB[8];
  {
    const ushort* arow = osum + (size_t)(blockIdx.x * 64 + n) * 256;
#pragma unroll
    for (int kc = 0; kc < 8; ++kc)
      xfA[kc] = *(const short8*)(arow + kc * 32 + quad * 8);
  }

#pragma unroll
  for (int tt = 0; tt < 4; ++tt) {
    short8* cur = (tt & 1) ? xfB : xfA;
    short8* nxt = (tt & 1) ? xfA : xfB;
    if (tt < 3) {
      const ushort* arow = osum + (size_t)(blockIdx.x * 64 + (tt + 1) * 16 + n) * 256;
#pragma unroll
      for (int kc = 0; kc < 8; ++kc)
        nxt[kc] = *(const short8*)(arow + kc * 32 + quad * 8);
    }
    int tok = blockIdx.x * 64 + tt * 16 + n;
    f32x4 acc[2] = {{0.f, 0.f, 0.f, 0.f}, {0.f, 0.f, 0.f, 0.f}};
#pragma unroll
    for (int ct = 0; ct < 2; ++ct)
#pragma unroll
      for (int kc = 0; kc < 8; ++kc)
        acc[ct] = __builtin_amdgcn_mfma_f32_16x16x32_bf16(wfrag[ct][kc], cur[kc], acc[ct], 0, 0, 0);
#pragma unroll
    for (int ct = 0; ct < 2; ++ct) {
      int c = cbase + ct * 16 + quad * 4;
      float* bp = (float*)&bt[ct];
      float4 st;
      st.x = acc[ct][0] + 2.0f * bp[0];
      st.y = acc[ct][1] + 2.0f * bp[1];
      st.z = acc[ct][2] + 2.0f * bp[2];
      st.w = acc[ct][3] + 2.0f * bp[3];
      *(float4*)(out + (size_t)tok * 256 + c) = st;
    }
  }
}

extern "C" void kernel_launch(void* const* d_in, const int* in_sizes, int n_in,
                              void* d_out, int out_size, void* d_ws, size_t ws_size,
                              hipStream_t stream) {
  const float* x   = (const float*)d_in[0];
  const float* lng = (const float*)d_in[1];
  const float* lnb = (const float*)d_in[2];
  const float* Wq  = (const float*)d_in[3];
  const float* bq  = (const float*)d_in[4];
  const float* Wk  = (const float*)d_in[5];
  const float* bk  = (const float*)d_in[6];
  const float* Wv  = (const float*)d_in[7];
  const float* bv  = (const float*)d_in[8];
  const float* Wo  = (const float*)d_in[9];
  const float* bo  = (const float*)d_in[10];
  float* out = (float*)d_out;

  ushort* ws = (ushort*)d_ws;
  const size_t XN  = (size_t)49152 * 256;      // 12,582,912
  const size_t QKV = (size_t)64 * 2048 * 32;   //  4,194,304
  ushort* xn   = ws;
  ushort* wbf  = xn + XN;          // [Wq|Wk|Wv|Wo] x 65536
  ushort* qb   = wbf + 4 * 65536;
  ushort* keb  = qb  + QKV;
  ushort* vTe  = keb + QKV;
  ushort* klb  = vTe + QKV;
  ushort* vTl  = klb + QKV;
  ushort* osum = vTl + QKV;

  hipLaunchKernelGGL(ln_wcast_kernel, dim3(12544), dim3(256), 0, stream,
                     x, lng, lnb, Wq, Wk, Wv, Wo, xn, wbf);
  hipLaunchKernelGGL(proj_kernel, dim3(128, 2, 5), dim3(256), 0, stream,
                     xn, wbf, wbf + 65536, wbf + 131072, bq, bk, bv,
                     qb, keb, vTe, klb, vTl);
  hipLaunchKernelGGL(attn_kernel, dim3(16, 64), dim3(256), 0, stream,
                     qb, keb, vTe, klb, vTl, osum);
  hipLaunchKernelGGL(outproj_kernel, dim3(256, 2), dim3(256), 0, stream,
                     osum, wbf + 196608, bo, out);
}

// Round 5
// 349.270 us; speedup vs baseline: 1.0394x; 1.0394x over previous
//
#include <hip/hip_runtime.h>
#include <hip/hip_bf16.h>
#include <math.h>

#define LN_EPS 1e-5f
// dim^-0.5 * log2(e): folded into q so softmax is exp2(s) with no muls
#define QSCALE 0.09016844005556021f

typedef __attribute__((ext_vector_type(8))) short short8;
typedef __attribute__((ext_vector_type(4))) float f32x4;

__device__ inline ushort f2bf(float f) {
  __hip_bfloat16 h = __float2bfloat16(f);
  return *reinterpret_cast<ushort*>(&h);
}

// Shapes (fixed): b=8, n=2048/stream, 3 streams, dim=256, heads=8, d=32.
// xn (bf16): [8*6144][256].  q/k (bf16): [bh][2048][32].  vT (bf16): [bh][32][2048].
// osum (bf16): [b*2048][256].

// ---------------------- fused: LN-normalize -> bf16  +  weight cast -> bf16
__global__ __launch_bounds__(256) void ln_wcast_kernel(
    const float* __restrict__ x, const float* __restrict__ lng,
    const float* __restrict__ lnb,
    const float* __restrict__ Wq, const float* __restrict__ Wk,
    const float* __restrict__ Wv, const float* __restrict__ Wo,
    ushort* __restrict__ xn, ushort* __restrict__ wbf) {
  if (blockIdx.x < 256) {
    int t = blockIdx.x * 256 + threadIdx.x;
    int e0 = t * 4;
    int m = e0 >> 16, off = e0 & 65535;
    const float* src = (m == 0) ? Wq : (m == 1) ? Wk : (m == 2) ? Wv : Wo;
    float4 v = *(const float4*)(src + off);
    ushort4 o;
    o.x = f2bf(v.x); o.y = f2bf(v.y); o.z = f2bf(v.z); o.w = f2bf(v.w);
    *(ushort4*)(wbf + m * 65536 + off) = o;
    return;
  }
  int w = threadIdx.x >> 6;
  int lane = threadIdx.x & 63;
  size_t token = (size_t)(blockIdx.x - 256) * 4 + w;
  float4 v = *(const float4*)(x + token * 256 + lane * 4);
  float s  = v.x + v.y + v.z + v.w;
  float s2 = v.x * v.x + v.y * v.y + v.z * v.z + v.w * v.w;
#pragma unroll
  for (int off = 32; off >= 1; off >>= 1) {
    s  += __shfl_xor(s, off, 64);
    s2 += __shfl_xor(s2, off, 64);
  }
  float mu  = s * (1.0f / 256.0f);
  float var = s2 * (1.0f / 256.0f) - mu * mu;
  float rs  = rsqrtf(var + LN_EPS);
  float4 g = *(const float4*)(lng + lane * 4);
  float4 bb = *(const float4*)(lnb + lane * 4);
  ushort4 o;
  o.x = f2bf((v.x - mu) * rs * g.x + bb.x);
  o.y = f2bf((v.y - mu) * rs * g.y + bb.y);
  o.z = f2bf((v.z - mu) * rs * g.z + bb.z);
  o.w = f2bf((v.w - mu) * rs * g.w + bb.w);
  *(ushort4*)(xn + token * 256 + lane * 4) = o;
}

// ------------------------------------------------- QKV projections (MFMA)
// z: 0=q (scaled, C^T) 1=k_e (C^T) 2=v_e (C -> vT) 3=k_l 4=v_l
// No LDS: both MFMA fragments are contiguous 16B global loads. (R3 form)
__global__ __launch_bounds__(256) void proj_kernel(
    const ushort* __restrict__ xn,
    const ushort* __restrict__ wq, const ushort* __restrict__ wk,
    const ushort* __restrict__ wv,
    const float* __restrict__ bq, const float* __restrict__ bk,
    const float* __restrict__ bv,
    ushort* __restrict__ qb, ushort* __restrict__ keb, ushort* __restrict__ vTe,
    ushort* __restrict__ klb, ushort* __restrict__ vTl) {
  int z = blockIdx.z;
  const ushort* W; const float* bias; ushort* out; int s; bool isV; float scl;
  if (z == 0)      { W = wq; bias = bq; out = qb;  s = 0; isV = false; scl = QSCALE; }
  else if (z == 1) { W = wk; bias = bk; out = keb; s = 1; isV = false; scl = 1.0f; }
  else if (z == 2) { W = wv; bias = bv; out = vTe; s = 1; isV = true;  scl = 1.0f; }
  else if (z == 3) { W = wk; bias = bk; out = klb; s = 2; isV = false; scl = 1.0f; }
  else             { W = wv; bias = bv; out = vTl; s = 2; isV = true;  scl = 1.0f; }

  int tid = threadIdx.x;
  int w = tid >> 6, lane = tid & 63;
  int n = lane & 15, quad = lane >> 4;
  int cbase = blockIdx.y * 128 + w * 32;

  short8 wfrag[2][8];
#pragma unroll
  for (int ct = 0; ct < 2; ++ct)
#pragma unroll
    for (int kc = 0; kc < 8; ++kc)
      wfrag[ct][kc] = *(const short8*)(W + (size_t)(cbase + ct * 16 + n) * 256 + kc * 32 + quad * 8);
  float4 bt[2]; float bsc[2];
  if (!isV) {
    bt[0] = *(const float4*)(bias + cbase + quad * 4);
    bt[1] = *(const float4*)(bias + cbase + 16 + quad * 4);
  } else {
    bsc[0] = bias[cbase + n];
    bsc[1] = bias[cbase + 16 + n];
  }

  for (int tt = 0; tt < 8; ++tt) {
    int t0 = blockIdx.x * 128 + tt * 16;
    int tok = t0 + n;
    int b = tok >> 11, n2 = tok & 2047;
    const ushort* xrow = xn + ((size_t)b * 6144 + s * 2048 + n2) * 256;
    short8 xf[8];
#pragma unroll
    for (int kc = 0; kc < 8; ++kc)
      xf[kc] = *(const short8*)(xrow + kc * 32 + quad * 8);
    f32x4 acc[2] = {{0.f, 0.f, 0.f, 0.f}, {0.f, 0.f, 0.f, 0.f}};
#pragma unroll
    for (int ct = 0; ct < 2; ++ct)
#pragma unroll
      for (int kc = 0; kc < 8; ++kc)
        acc[ct] = isV
          ? __builtin_amdgcn_mfma_f32_16x16x32_bf16(xf[kc], wfrag[ct][kc], acc[ct], 0, 0, 0)
          : __builtin_amdgcn_mfma_f32_16x16x32_bf16(wfrag[ct][kc], xf[kc], acc[ct], 0, 0, 0);

    if (!isV) {
#pragma unroll
      for (int ct = 0; ct < 2; ++ct) {
        int c = cbase + ct * 16 + quad * 4;
        int h = c >> 5, d = c & 31;
        float* bp = (float*)&bt[ct];
        ushort4 st;
        st.x = f2bf((acc[ct][0] + bp[0]) * scl);
        st.y = f2bf((acc[ct][1] + bp[1]) * scl);
        st.z = f2bf((acc[ct][2] + bp[2]) * scl);
        st.w = f2bf((acc[ct][3] + bp[3]) * scl);
        *(ushort4*)(out + (((size_t)(b * 8 + h) * 2048) + n2) * 32 + d) = st;
      }
    } else {
      int tq0 = t0 + quad * 4;
      int b2 = tq0 >> 11, n2q = tq0 & 2047;
#pragma unroll
      for (int ct = 0; ct < 2; ++ct) {
        int c = cbase + ct * 16 + n;
        int h = c >> 5, d = c & 31;
        ushort4 st;
        st.x = f2bf(acc[ct][0] + bsc[ct]);
        st.y = f2bf(acc[ct][1] + bsc[ct]);
        st.z = f2bf(acc[ct][2] + bsc[ct]);
        st.w = f2bf(acc[ct][3] + bsc[ct]);
        *(ushort4*)(out + (((size_t)(b2 * 8 + h) * 32) + d) * 2048 + n2q) = st;
      }
    }
  }
}

// ------------------------------------------------ flash attention bf16 MFMA
// No K-loop barriers: K/V^T fragments loaded straight from global in MFMA
// A-operand layout (L1 serves the 4-wave intra-block reuse).  Software-
// pipelined: registers double-buffer the next tile's K/V loads so the
// vmcnt wait lands after a full iteration of MFMA+exp+LDS work.
__device__ __forceinline__ void attn_load(
    const ushort* __restrict__ K, const ushort* __restrict__ VT, int kt0,
    int n, int quad, short8 kf[4], short8 vf[4]) {
#pragma unroll
  for (int t4 = 0; t4 < 4; ++t4)
    kf[t4] = *(const short8*)(K + (size_t)(kt0 + t4 * 16 + n) * 32 + quad * 8);
#pragma unroll
  for (int dh = 0; dh < 2; ++dh)
#pragma unroll
    for (int kc = 0; kc < 2; ++kc)
      vf[dh * 2 + kc] = *(const short8*)(VT + (size_t)(dh * 16 + n) * 2048 + kt0 + kc * 32 + quad * 8);
}

__device__ __forceinline__ void attn_step(
    const short8 kf[4], const short8 vf[4], const short8 qfrag[2],
    f32x4 oacc[2][2], float l[2], short* __restrict__ PtW, int n, int quad) {
  f32x4 sacc[2][4];
#pragma unroll
  for (int gq = 0; gq < 2; ++gq)
#pragma unroll
    for (int t4 = 0; t4 < 4; ++t4) {
      f32x4 z = {0.f, 0.f, 0.f, 0.f};
      sacc[gq][t4] = __builtin_amdgcn_mfma_f32_16x16x32_bf16(kf[t4], qfrag[gq], z, 0, 0, 0);
    }
#pragma unroll
  for (int gq = 0; gq < 2; ++gq) {
    float ls = 0.f;
#pragma unroll
    for (int t4 = 0; t4 < 4; ++t4) {
      float p0 = __builtin_amdgcn_exp2f(sacc[gq][t4][0]);
      float p1 = __builtin_amdgcn_exp2f(sacc[gq][t4][1]);
      float p2 = __builtin_amdgcn_exp2f(sacc[gq][t4][2]);
      float p3 = __builtin_amdgcn_exp2f(sacc[gq][t4][3]);
      ls += p0 + p1 + p2 + p3;
      ushort4 pk;
      pk.x = f2bf(p0); pk.y = f2bf(p1); pk.z = f2bf(p2); pk.w = f2bf(p3);
      *(ushort4*)&PtW[gq * 1152 + n * 72 + t4 * 16 + quad * 4] = pk;
    }
    ls += __shfl_xor(ls, 16, 64);
    ls += __shfl_xor(ls, 32, 64);
    l[gq] += ls;
  }
#pragma unroll
  for (int gq = 0; gq < 2; ++gq)
#pragma unroll
    for (int kc = 0; kc < 2; ++kc) {
      short8 bfrag = *(const short8*)&PtW[gq * 1152 + n * 72 + kc * 32 + quad * 8];
#pragma unroll
      for (int dh = 0; dh < 2; ++dh)
        oacc[gq][dh] = __builtin_amdgcn_mfma_f32_16x16x32_bf16(vf[dh * 2 + kc], bfrag, oacc[gq][dh], 0, 0, 0);
    }
}

__global__ __launch_bounds__(256) void attn_kernel(
    const ushort* __restrict__ q,
    const ushort* __restrict__ ke, const ushort* __restrict__ vTe,
    const ushort* __restrict__ kl, const ushort* __restrict__ vTl,
    ushort* __restrict__ osum) {
  __shared__ __align__(16) short Pt[4][2][16 * 72];  // [wave][qgroup][qrow][64+8pad]

  int tid = threadIdx.x;
  int w = tid >> 6, lane = tid & 63;
  int n = lane & 15, quad = lane >> 4;
  short* PtW = &Pt[w][0][0];

  // swizzle: one bh's 16 q-blocks land on one XCD (id%8) for L2 reuse
  int lin = blockIdx.y * 16 + blockIdx.x;
  int g = (lin & 7) * 128 + (lin >> 3);
  int bh = g >> 4;
  int q0 = (g & 15) * 128;

  short8 qfrag[2];
  qfrag[0] = *(const short8*)(q + ((size_t)bh * 2048 + q0 + w * 16 + n) * 32 + quad * 8);
  qfrag[1] = *(const short8*)(q + ((size_t)bh * 2048 + q0 + 64 + w * 16 + n) * 32 + quad * 8);

  f32x4 out_acc[2][2] = {{{0.f,0.f,0.f,0.f},{0.f,0.f,0.f,0.f}},
                         {{0.f,0.f,0.f,0.f},{0.f,0.f,0.f,0.f}}};

  for (int s = 0; s < 2; ++s) {
    const ushort* K  = (s == 0 ? ke : kl) + (size_t)bh * 2048 * 32;
    const ushort* VT = (s == 0 ? vTe : vTl) + (size_t)bh * 32 * 2048;
    float l[2] = {0.f, 0.f};
    f32x4 oacc[2][2] = {{{0.f,0.f,0.f,0.f},{0.f,0.f,0.f,0.f}},
                        {{0.f,0.f,0.f,0.f},{0.f,0.f,0.f,0.f}}};

    short8 kfA[4], vfA[4], kfB[4], vfB[4];
    attn_load(K, VT, 0, n, quad, kfA, vfA);
    for (int j2 = 0; j2 < 16; ++j2) {
      attn_load(K, VT, (2 * j2 + 1) * 64, n, quad, kfB, vfB);
      attn_step(kfA, vfA, qfrag, oacc, l, PtW, n, quad);
      if (j2 < 15) attn_load(K, VT, (2 * j2 + 2) * 64, n, quad, kfA, vfA);
      attn_step(kfB, vfB, qfrag, oacc, l, PtW, n, quad);
    }
#pragma unroll
    for (int gq = 0; gq < 2; ++gq) {
      float inv = 1.0f / l[gq];
      out_acc[gq][0] += oacc[gq][0] * inv;
      out_acc[gq][1] += oacc[gq][1] * inv;
    }
  }

  // transpose O^T -> O per wave/group via Pt region (16x36 fp32 fits exactly)
  int b = bh >> 3, h = bh & 7;
  int qrow = lane >> 2, c4 = (lane & 3) * 4;
#pragma unroll
  for (int gq = 0; gq < 2; ++gq) {
    float* Os = (float*)&Pt[w][gq][0];
#pragma unroll
    for (int dh = 0; dh < 2; ++dh)
      *(f32x4*)&Os[n * 36 + dh * 16 + quad * 4] = out_acc[gq][dh];
    ushort* orow = osum + ((size_t)b * 2048 + q0 + gq * 64 + w * 16 + qrow) * 256 + h * 32;
#pragma unroll
    for (int off = 0; off < 32; off += 16) {
      f32x4 vv = *(f32x4*)&Os[qrow * 36 + off + c4];
      ushort4 st;
      st.x = f2bf(vv[0]); st.y = f2bf(vv[1]); st.z = f2bf(vv[2]); st.w = f2bf(vv[3]);
      *(ushort4*)(orow + off + c4) = st;
    }
  }
}

// ------------------------------------------- output projection (MFMA, C^T)
// out[t][c] = sum_k osum[t][k]*Wo[c][k] + 2*bo[c], fp32 out.  (R3 form)
__global__ __launch_bounds__(256) void outproj_kernel(
    const ushort* __restrict__ osum, const ushort* __restrict__ wo,
    const float* __restrict__ bo, float* __restrict__ out) {
  int tid = threadIdx.x;
  int w = tid >> 6, lane = tid & 63;
  int n = lane & 15, quad = lane >> 4;
  int cbase = blockIdx.y * 128 + w * 32;

  short8 wfrag[2][8];
#pragma unroll
  for (int ct = 0; ct < 2; ++ct)
#pragma unroll
    for (int kc = 0; kc < 8; ++kc)
      wfrag[ct][kc] = *(const short8*)(wo + (size_t)(cbase + ct * 16 + n) * 256 + kc * 32 + quad * 8);
  float4 bt[2];
  bt[0] = *(const float4*)(bo + cbase + quad * 4);
  bt[1] = *(const float4*)(bo + cbase + 16 + quad * 4);

  for (int tt = 0; tt < 8; ++tt) {
    int t0 = blockIdx.x * 128 + tt * 16;
    int tok = t0 + n;
    const ushort* arow = osum + (size_t)tok * 256;
    short8 xf[8];
#pragma unroll
    for (int kc = 0; kc < 8; ++kc)
      xf[kc] = *(const short8*)(arow + kc * 32 + quad * 8);
    f32x4 acc[2] = {{0.f, 0.f, 0.f, 0.f}, {0.f, 0.f, 0.f, 0.f}};
#pragma unroll
    for (int ct = 0; ct < 2; ++ct)
#pragma unroll
      for (int kc = 0; kc < 8; ++kc)
        acc[ct] = __builtin_amdgcn_mfma_f32_16x16x32_bf16(wfrag[ct][kc], xf[kc], acc[ct], 0, 0, 0);
#pragma unroll
    for (int ct = 0; ct < 2; ++ct) {
      int c = cbase + ct * 16 + quad * 4;
      float* bp = (float*)&bt[ct];
      float4 st;
      st.x = acc[ct][0] + 2.0f * bp[0];
      st.y = acc[ct][1] + 2.0f * bp[1];
      st.z = acc[ct][2] + 2.0f * bp[2];
      st.w = acc[ct][3] + 2.0f * bp[3];
      *(float4*)(out + (size_t)tok * 256 + c) = st;
    }
  }
}

extern "C" void kernel_launch(void* const* d_in, const int* in_sizes, int n_in,
                              void* d_out, int out_size, void* d_ws, size_t ws_size,
                              hipStream_t stream) {
  const float* x   = (const float*)d_in[0];
  const float* lng = (const float*)d_in[1];
  const float* lnb = (const float*)d_in[2];
  const float* Wq  = (const float*)d_in[3];
  const float* bq  = (const float*)d_in[4];
  const float* Wk  = (const float*)d_in[5];
  const float* bk  = (const float*)d_in[6];
  const float* Wv  = (const float*)d_in[7];
  const float* bv  = (const float*)d_in[8];
  const float* Wo  = (const float*)d_in[9];
  const float* bo  = (const float*)d_in[10];
  float* out = (float*)d_out;

  ushort* ws = (ushort*)d_ws;
  const size_t XN  = (size_t)49152 * 256;      // 12,582,912
  const size_t QKV = (size_t)64 * 2048 * 32;   //  4,194,304
  ushort* xn   = ws;
  ushort* wbf  = xn + XN;          // [Wq|Wk|Wv|Wo] x 65536
  ushort* qb   = wbf + 4 * 65536;
  ushort* keb  = qb  + QKV;
  ushort* vTe  = keb + QKV;
  ushort* klb  = vTe + QKV;
  ushort* vTl  = klb + QKV;
  ushort* osum = vTl + QKV;

  hipLaunchKernelGGL(ln_wcast_kernel, dim3(12544), dim3(256), 0, stream,
                     x, lng, lnb, Wq, Wk, Wv, Wo, xn, wbf);
  hipLaunchKernelGGL(proj_kernel, dim3(128, 2, 5), dim3(256), 0, stream,
                     xn, wbf, wbf + 65536, wbf + 131072, bq, bk, bv,
                     qb, keb, vTe, klb, vTl);
  hipLaunchKernelGGL(attn_kernel, dim3(16, 64), dim3(256), 0, stream,
                     qb, keb, vTe, klb, vTl, osum);
  hipLaunchKernelGGL(outproj_kernel, dim3(128, 2), dim3(256), 0, stream,
                     osum, wbf + 196608, bo, out);
}